// Round 2
// baseline (1052.980 us; speedup 1.0000x reference)
//
#include <hip/hip_runtime.h>
#include <stdint.h>

#define H_DIM 1024
#define I_DIM 2048
#define NEXP 8
#define T_TOK 8192

typedef _Float16 f16;
typedef __attribute__((ext_vector_type(2))) __fp16 fp16x2;
typedef __attribute__((ext_vector_type(8))) _Float16 f16x8;
typedef __attribute__((ext_vector_type(4))) float fvec4;
typedef __attribute__((ext_vector_type(4))) float f32x4;
typedef __attribute__((ext_vector_type(4))) unsigned int uvec4;
typedef __attribute__((ext_vector_type(2))) unsigned int uvec2;

union H8 { fp16x2 h2[4]; uvec4 v; };
union H4 { fp16x2 h2[2]; uvec2 v; };

// async global->LDS, 16B per lane; LDS dest is wave-uniform base + lane*16
__device__ __forceinline__ void async_copy16(const void* g, void* l) {
    __builtin_amdgcn_global_load_lds(
        (__attribute__((address_space(1))) void*)(uintptr_t)g,
        (__attribute__((address_space(3))) void*)l,
        16, 0, 0);
}

// ---------------- init: zero d_out + expert counts ----------------
__global__ void init_kernel(fvec4* __restrict__ out, int* __restrict__ cnt) {
    size_t i = (size_t)blockIdx.x * 256 + threadIdx.x;
    out[i] = (fvec4)0.f;  // grid sized exactly: 8192 blocks * 256 = 2,097,152 float4
    if (blockIdx.x == 0 && threadIdx.x < NEXP) cnt[threadIdx.x] = 0;
}

// ---------------- convert x fp32 -> fp16 ----------------
__global__ void cvt_x_kernel(const float* __restrict__ x, f16* __restrict__ xb) {
    size_t i = (size_t)blockIdx.x * 256 + threadIdx.x;  // 8 floats per thread
    const fvec4* p = (const fvec4*)x + i * 2;
    fvec4 a = p[0], b = p[1];
    H8 h;
    h.h2[0] = __builtin_amdgcn_cvt_pkrtz(a.x, a.y);
    h.h2[1] = __builtin_amdgcn_cvt_pkrtz(a.z, a.w);
    h.h2[2] = __builtin_amdgcn_cvt_pkrtz(b.x, b.y);
    h.h2[3] = __builtin_amdgcn_cvt_pkrtz(b.z, b.w);
    ((uvec4*)xb)[i] = h.v;
}

// ---------------- router: fp32 logits, top-2, scatter to expert lists ----------------
__global__ void router_kernel(const float* __restrict__ x, const float* __restrict__ rw,
                              int* __restrict__ cnt, int* __restrict__ tok,
                              float* __restrict__ wl) {
    int wid = (blockIdx.x * blockDim.x + threadIdx.x) >> 6;  // token id
    int lane = threadIdx.x & 63;
    if (wid >= T_TOK) return;
    const fvec4* xr = (const fvec4*)(x + (size_t)wid * H_DIM);
    float acc[NEXP];
#pragma unroll
    for (int e = 0; e < NEXP; ++e) acc[e] = 0.f;
#pragma unroll
    for (int p = 0; p < 4; ++p) {
        int c4 = p * 64 + lane;
        fvec4 xv = xr[c4];
#pragma unroll
        for (int e = 0; e < NEXP; ++e) {
            fvec4 wv = ((const fvec4*)(rw + (size_t)e * H_DIM))[c4];
            acc[e] += xv.x * wv.x + xv.y * wv.y + xv.z * wv.z + xv.w * wv.w;
        }
    }
#pragma unroll
    for (int e = 0; e < NEXP; ++e) {
        float v = acc[e];
#pragma unroll
        for (int s = 32; s > 0; s >>= 1) v += __shfl_xor(v, s, 64);
        acc[e] = v;
    }
    if (lane == 0) {
        int i0 = 0; float m0 = acc[0];
#pragma unroll
        for (int e = 1; e < NEXP; ++e) if (acc[e] > m0) { m0 = acc[e]; i0 = e; }
        int i1 = -1; float m1 = -1e30f;
#pragma unroll
        for (int e = 0; e < NEXP; ++e) if (e != i0 && acc[e] > m1) { m1 = acc[e]; i1 = e; }
        float w0 = 1.f / (1.f + __expf(m1 - m0));  // normalized top-2 weights
        float w1 = 1.f - w0;
        int p0 = atomicAdd(&cnt[i0], 1);
        tok[i0 * T_TOK + p0] = wid; wl[i0 * T_TOK + p0] = w0;
        int p1 = atomicAdd(&cnt[i1], 1);
        tok[i1 * T_TOK + p1] = wid; wl[i1 * T_TOK + p1] = w1;
    }
}

// ---------------- exclusive scan of counts (8 values) ----------------
__global__ void scan_kernel(const int* __restrict__ cnt, int* __restrict__ offs) {
    if (threadIdx.x == 0) {
        int s = 0;
        for (int e = 0; e < NEXP; ++e) { offs[e] = s; s += cnt[e]; }
    }
}

// ---------------- GU: mid = silu(Xe*Wg^T) .* (Xe*Wu^T), grouped-gather GEMM ----------------
__global__ __launch_bounds__(256) void gu_kernel(
    const f16* __restrict__ xb, const float* __restrict__ wg, const float* __restrict__ wu,
    const int* __restrict__ cnt, const int* __restrict__ offs,
    const int* __restrict__ tok, f16* __restrict__ mid) {
    const int e = blockIdx.z, rt = blockIdx.y, ct = blockIdx.x;
    const int count = cnt[e];
    if (rt * 128 >= count) return;
    const int offs_e = offs[e];

    __shared__ f16 As[128 * 64];
    __shared__ f16 Bg[128 * 64];
    __shared__ f16 Bu[128 * 64];

    const int tid = threadIdx.x;
    const int w = tid >> 6, lane = tid & 63;
    const int wm = w & 1, wn = w >> 1;
    const int qr = lane >> 4, lc = lane & 15;

    // A staging (gathered token rows, fp16 source -> global_load_lds)
    const f16* gA[4]; f16* lA[4];
#pragma unroll
    for (int it = 0; it < 4; ++it) {
        int row = (it * 4 + w) * 8 + (lane >> 3);
        int lr2 = rt * 128 + row; if (lr2 > count - 1) lr2 = count - 1;
        int t = tok[e * T_TOK + lr2];
        gA[it] = xb + (size_t)t * H_DIM + (lane & 7) * 8;
        lA[it] = &As[(it * 4 + w) * 8 * 64];
    }
    // B staging (fp32 weights -> cvt -> LDS). row = (tid>>4) + g8*16, 4 fp32 cols/thread
    const int brow = tid >> 4, bcol = (tid & 15) * 4;
    const float* pg = wg + ((size_t)e * I_DIM + ct * 128 + brow) * H_DIM + bcol;
    const float* pu = wu + ((size_t)e * I_DIM + ct * 128 + brow) * H_DIM + bcol;
    f16* lBg = &Bg[brow * 64 + bcol];
    f16* lBu = &Bu[brow * 64 + bcol];

    f32x4 accg[4][4], accu[4][4];
#pragma unroll
    for (int i = 0; i < 4; ++i)
#pragma unroll
        for (int j = 0; j < 4; ++j) { accg[i][j] = (f32x4)0.f; accu[i][j] = (f32x4)0.f; }

    for (int ks = 0; ks < H_DIM / 64; ++ks) {
        const int k0 = ks * 64;
#pragma unroll
        for (int it = 0; it < 4; ++it) async_copy16(gA[it] + k0, lA[it]);
#pragma unroll
        for (int g8 = 0; g8 < 8; ++g8) {
            fvec4 a = *(const fvec4*)(pg + (size_t)g8 * 16 * H_DIM + k0);
            H4 h;
            h.h2[0] = __builtin_amdgcn_cvt_pkrtz(a.x, a.y);
            h.h2[1] = __builtin_amdgcn_cvt_pkrtz(a.z, a.w);
            *(uvec2*)(lBg + g8 * 16 * 64) = h.v;
            fvec4 b = *(const fvec4*)(pu + (size_t)g8 * 16 * H_DIM + k0);
            h.h2[0] = __builtin_amdgcn_cvt_pkrtz(b.x, b.y);
            h.h2[1] = __builtin_amdgcn_cvt_pkrtz(b.z, b.w);
            *(uvec2*)(lBu + g8 * 16 * 64) = h.v;
        }
        __syncthreads();
#pragma unroll
        for (int kk = 0; kk < 64; kk += 32) {
            f16x8 af[4], bg[4], bu[4];
#pragma unroll
            for (int mi = 0; mi < 4; ++mi)
                af[mi] = *(const f16x8*)&As[(wm * 64 + mi * 16 + lc) * 64 + kk + qr * 8];
#pragma unroll
            for (int ni = 0; ni < 4; ++ni) {
                bg[ni] = *(const f16x8*)&Bg[(wn * 64 + ni * 16 + lc) * 64 + kk + qr * 8];
                bu[ni] = *(const f16x8*)&Bu[(wn * 64 + ni * 16 + lc) * 64 + kk + qr * 8];
            }
#pragma unroll
            for (int mi = 0; mi < 4; ++mi)
#pragma unroll
                for (int ni = 0; ni < 4; ++ni) {
                    accg[mi][ni] = __builtin_amdgcn_mfma_f32_16x16x32_f16(af[mi], bg[ni], accg[mi][ni], 0, 0, 0);
                    accu[mi][ni] = __builtin_amdgcn_mfma_f32_16x16x32_f16(af[mi], bu[ni], accu[mi][ni], 0, 0, 0);
                }
        }
        __syncthreads();
    }
    // epilogue: silu(g)*u -> mid fp16
#pragma unroll
    for (int mi = 0; mi < 4; ++mi)
#pragma unroll
        for (int ni = 0; ni < 4; ++ni)
#pragma unroll
            for (int r = 0; r < 4; ++r) {
                int lrow = rt * 128 + wm * 64 + mi * 16 + qr * 4 + r;
                if (lrow < count) {
                    float g = accg[mi][ni][r], u = accu[mi][ni][r];
                    float s = g / (1.f + __expf(-g)) * u;
                    mid[(size_t)(offs_e + lrow) * I_DIM + ct * 128 + wn * 64 + ni * 16 + lc] = (f16)s;
                }
            }
}

// ---------------- DOWN: out[t] += w * (mid_e * Wd^T), atomic scatter ----------------
__global__ __launch_bounds__(256) void down_kernel(
    const f16* __restrict__ mid, const float* __restrict__ wd,
    const int* __restrict__ cnt, const int* __restrict__ offs,
    const int* __restrict__ tok, const float* __restrict__ wl,
    float* __restrict__ out) {
    const int e = blockIdx.z, rt = blockIdx.y, ct = blockIdx.x;  // ct: 0..7
    const int count = cnt[e];
    if (rt * 128 >= count) return;
    const int offs_e = offs[e];

    __shared__ f16 As[128 * 64];
    __shared__ f16 Bd[128 * 64];

    const int tid = threadIdx.x;
    const int w = tid >> 6, lane = tid & 63;
    const int wm = w & 1, wn = w >> 1;
    const int qr = lane >> 4, lc = lane & 15;

    const f16* gA[4]; f16* lA[4];
#pragma unroll
    for (int it = 0; it < 4; ++it) {
        int row = (it * 4 + w) * 8 + (lane >> 3);
        int lr2 = rt * 128 + row; if (lr2 > count - 1) lr2 = count - 1;
        gA[it] = mid + (size_t)(offs_e + lr2) * I_DIM + (lane & 7) * 8;
        lA[it] = &As[(it * 4 + w) * 8 * 64];
    }
    const int brow = tid >> 4, bcol = (tid & 15) * 4;
    const float* pd = wd + ((size_t)e * H_DIM + ct * 128 + brow) * I_DIM + bcol;
    f16* lBd = &Bd[brow * 64 + bcol];

    f32x4 acc[4][4];
#pragma unroll
    for (int i = 0; i < 4; ++i)
#pragma unroll
        for (int j = 0; j < 4; ++j) acc[i][j] = (f32x4)0.f;

    for (int ks = 0; ks < I_DIM / 64; ++ks) {
        const int k0 = ks * 64;
#pragma unroll
        for (int it = 0; it < 4; ++it) async_copy16(gA[it] + k0, lA[it]);
#pragma unroll
        for (int g8 = 0; g8 < 8; ++g8) {
            fvec4 a = *(const fvec4*)(pd + (size_t)g8 * 16 * I_DIM + k0);
            H4 h;
            h.h2[0] = __builtin_amdgcn_cvt_pkrtz(a.x, a.y);
            h.h2[1] = __builtin_amdgcn_cvt_pkrtz(a.z, a.w);
            *(uvec2*)(lBd + g8 * 16 * 64) = h.v;
        }
        __syncthreads();
#pragma unroll
        for (int kk = 0; kk < 64; kk += 32) {
            f16x8 af[4], bf[4];
#pragma unroll
            for (int mi = 0; mi < 4; ++mi)
                af[mi] = *(const f16x8*)&As[(wm * 64 + mi * 16 + lc) * 64 + kk + qr * 8];
#pragma unroll
            for (int ni = 0; ni < 4; ++ni)
                bf[ni] = *(const f16x8*)&Bd[(wn * 64 + ni * 16 + lc) * 64 + kk + qr * 8];
#pragma unroll
            for (int mi = 0; mi < 4; ++mi)
#pragma unroll
                for (int ni = 0; ni < 4; ++ni)
                    acc[mi][ni] = __builtin_amdgcn_mfma_f32_16x16x32_f16(af[mi], bf[ni], acc[mi][ni], 0, 0, 0);
        }
        __syncthreads();
    }
#pragma unroll
    for (int mi = 0; mi < 4; ++mi)
#pragma unroll
        for (int ni = 0; ni < 4; ++ni)
#pragma unroll
            for (int r = 0; r < 4; ++r) {
                int lrow = rt * 128 + wm * 64 + mi * 16 + qr * 4 + r;
                if (lrow < count) {
                    int t = tok[e * T_TOK + lrow];
                    float wt = wl[e * T_TOK + lrow];
                    atomicAdd(&out[(size_t)t * H_DIM + ct * 128 + wn * 64 + ni * 16 + lc],
                              wt * acc[mi][ni][r]);
                }
            }
}

extern "C" void kernel_launch(void* const* d_in, const int* in_sizes, int n_in,
                              void* d_out, int out_size, void* d_ws, size_t ws_size,
                              hipStream_t stream) {
    (void)in_sizes; (void)n_in; (void)out_size; (void)ws_size;
    const float* x  = (const float*)d_in[0];
    const float* rw = (const float*)d_in[1];
    const float* wg = (const float*)d_in[2];
    const float* wu = (const float*)d_in[3];
    const float* wd = (const float*)d_in[4];
    float* out = (float*)d_out;

    uint8_t* ws = (uint8_t*)d_ws;
    int*   cnt  = (int*)(ws + 0);
    int*   offs = (int*)(ws + 64);
    int*   tok  = (int*)(ws + 4096);                     // 8*8192 ints   = 262144 B
    float* wl   = (float*)(ws + 4096 + 262144);          // 8*8192 floats = 262144 B
    f16*   xb   = (f16*)(ws + 528384);                   // 8192*1024 f16 = 16777216 B
    f16*   mid  = (f16*)(ws + 528384 + 16777216);        // 16384*2048 f16 = 67108864 B
    // total ws use: 84,414,464 B

    hipLaunchKernelGGL(init_kernel, dim3(8192), dim3(256), 0, stream, (fvec4*)out, cnt);
    hipLaunchKernelGGL(cvt_x_kernel, dim3(4096), dim3(256), 0, stream, x, xb);
    hipLaunchKernelGGL(router_kernel, dim3(2048), dim3(256), 0, stream, x, rw, cnt, tok, wl);
    hipLaunchKernelGGL(scan_kernel, dim3(1), dim3(64), 0, stream, cnt, offs);
    hipLaunchKernelGGL(gu_kernel, dim3(16, 64, 8), dim3(256), 0, stream, xb, wg, wu, cnt, offs, tok, mid);
    hipLaunchKernelGGL(down_kernel, dim3(8, 64, 8), dim3(256), 0, stream, mid, wd, cnt, offs, tok, wl, out);
}

// Round 3
// 1000.919 us; speedup vs baseline: 1.0520x; 1.0520x over previous
//
#include <hip/hip_runtime.h>
#include <stdint.h>

#define H_DIM 1024
#define I_DIM 2048
#define NEXP 8
#define T_TOK 8192

typedef _Float16 f16;
typedef __attribute__((ext_vector_type(2))) __fp16 fp16x2;
typedef __attribute__((ext_vector_type(8))) _Float16 f16x8;
typedef __attribute__((ext_vector_type(4))) float fvec4;
typedef __attribute__((ext_vector_type(4))) float f32x4;
typedef __attribute__((ext_vector_type(4))) unsigned int uvec4;
typedef __attribute__((ext_vector_type(2))) unsigned int uvec2;

union H8 { fp16x2 h2[4]; uvec4 v; };

// async global->LDS, 16B per lane; LDS dest is wave-uniform base + lane*16
__device__ __forceinline__ void async_copy16(const void* g, void* l) {
    __builtin_amdgcn_global_load_lds(
        (__attribute__((address_space(1))) void*)(uintptr_t)g,
        (__attribute__((address_space(3))) void*)l,
        16, 0, 0);
}

// ---------------- init: zero d_out + expert counts ----------------
__global__ void init_kernel(fvec4* __restrict__ out, int* __restrict__ cnt) {
    size_t i = (size_t)blockIdx.x * 256 + threadIdx.x;
    out[i] = (fvec4)0.f;  // 8192 blocks * 256 = 2,097,152 float4 = 8M floats
    if (blockIdx.x == 0 && threadIdx.x < NEXP) cnt[threadIdx.x] = 0;
}

// ---------------- convert x fp32 -> fp16 ----------------
__global__ void cvt_x_kernel(const float* __restrict__ x, f16* __restrict__ xb) {
    size_t i = (size_t)blockIdx.x * 256 + threadIdx.x;  // 8 floats per thread
    const fvec4* p = (const fvec4*)x + i * 2;
    fvec4 a = p[0], b = p[1];
    H8 h;
    h.h2[0] = __builtin_amdgcn_cvt_pkrtz(a.x, a.y);
    h.h2[1] = __builtin_amdgcn_cvt_pkrtz(a.z, a.w);
    h.h2[2] = __builtin_amdgcn_cvt_pkrtz(b.x, b.y);
    h.h2[3] = __builtin_amdgcn_cvt_pkrtz(b.z, b.w);
    ((uvec4*)xb)[i] = h.v;
}

// ---------------- convert all three weight tensors fp32 -> fp16 ----------------
__global__ void cvt_w_kernel(const float* __restrict__ wg, const float* __restrict__ wu,
                             const float* __restrict__ wd,
                             f16* __restrict__ wgh, f16* __restrict__ wuh,
                             f16* __restrict__ wdh) {
    const float* src; f16* dst;
    if (blockIdx.y == 0)      { src = wg; dst = wgh; }
    else if (blockIdx.y == 1) { src = wu; dst = wuh; }
    else                      { src = wd; dst = wdh; }
    size_t i = (size_t)blockIdx.x * 256 + threadIdx.x;  // 8 floats per thread
    const fvec4* p = (const fvec4*)src + i * 2;
    fvec4 a = p[0], b = p[1];
    H8 h;
    h.h2[0] = __builtin_amdgcn_cvt_pkrtz(a.x, a.y);
    h.h2[1] = __builtin_amdgcn_cvt_pkrtz(a.z, a.w);
    h.h2[2] = __builtin_amdgcn_cvt_pkrtz(b.x, b.y);
    h.h2[3] = __builtin_amdgcn_cvt_pkrtz(b.z, b.w);
    ((uvec4*)dst)[i] = h.v;
}

// ---------------- router: fp32 logits, top-2, scatter to expert lists ----------------
__global__ void router_kernel(const float* __restrict__ x, const float* __restrict__ rw,
                              int* __restrict__ cnt, int* __restrict__ tok,
                              float* __restrict__ wl) {
    int wid = (blockIdx.x * blockDim.x + threadIdx.x) >> 6;  // token id
    int lane = threadIdx.x & 63;
    if (wid >= T_TOK) return;
    const fvec4* xr = (const fvec4*)(x + (size_t)wid * H_DIM);
    float acc[NEXP];
#pragma unroll
    for (int e = 0; e < NEXP; ++e) acc[e] = 0.f;
#pragma unroll
    for (int p = 0; p < 4; ++p) {
        int c4 = p * 64 + lane;
        fvec4 xv = xr[c4];
#pragma unroll
        for (int e = 0; e < NEXP; ++e) {
            fvec4 wv = ((const fvec4*)(rw + (size_t)e * H_DIM))[c4];
            acc[e] += xv.x * wv.x + xv.y * wv.y + xv.z * wv.z + xv.w * wv.w;
        }
    }
#pragma unroll
    for (int e = 0; e < NEXP; ++e) {
        float v = acc[e];
#pragma unroll
        for (int s = 32; s > 0; s >>= 1) v += __shfl_xor(v, s, 64);
        acc[e] = v;
    }
    if (lane == 0) {
        int i0 = 0; float m0 = acc[0];
#pragma unroll
        for (int e = 1; e < NEXP; ++e) if (acc[e] > m0) { m0 = acc[e]; i0 = e; }
        int i1 = -1; float m1 = -1e30f;
#pragma unroll
        for (int e = 0; e < NEXP; ++e) if (e != i0 && acc[e] > m1) { m1 = acc[e]; i1 = e; }
        float w0 = 1.f / (1.f + __expf(m1 - m0));  // normalized top-2 weights
        float w1 = 1.f - w0;
        int p0 = atomicAdd(&cnt[i0], 1);
        tok[i0 * T_TOK + p0] = wid; wl[i0 * T_TOK + p0] = w0;
        int p1 = atomicAdd(&cnt[i1], 1);
        tok[i1 * T_TOK + p1] = wid; wl[i1 * T_TOK + p1] = w1;
    }
}

// ---------------- exclusive scan of counts (8 values) ----------------
__global__ void scan_kernel(const int* __restrict__ cnt, int* __restrict__ offs) {
    if (threadIdx.x == 0) {
        int s = 0;
        for (int e = 0; e < NEXP; ++e) { offs[e] = s; s += cnt[e]; }
    }
}

// LDS tile layout: [128 rows][64 halfwords], row stride 128 B = 8 chunks of 16 B.
// XOR swizzle: global chunk c of row r lives at LDS chunk (c ^ (r&7)).
// Async staging: lane l of a wave slab writes LDS chunk (l&7) of row (l>>3),
// so lane l fetches GLOBAL chunk ((l&7) ^ (l>>3)).

// ---------------- GU: mid = silu(Xe*Wg^T) .* (Xe*Wu^T), grouped-gather GEMM ----------------
__global__ __launch_bounds__(256) void gu_kernel(
    const f16* __restrict__ xb, const f16* __restrict__ wgh, const f16* __restrict__ wuh,
    const int* __restrict__ cnt, const int* __restrict__ offs,
    const int* __restrict__ tok, f16* __restrict__ mid) {
    const int e = blockIdx.z, rt = blockIdx.y, ct = blockIdx.x;
    const int count = cnt[e];
    if (rt * 128 >= count) return;
    const int offs_e = offs[e];

    __shared__ f16 As[128 * 64];
    __shared__ f16 Bg[128 * 64];
    __shared__ f16 Bu[128 * 64];

    const int tid = threadIdx.x;
    const int w = tid >> 6, lane = tid & 63;
    const int wm = w & 1, wn = w >> 1;
    const int qr = lane >> 4, lc = lane & 15;

    const int rsl = lane >> 3;                // row within 8-row slab
    const int chk = (lane & 7) ^ rsl;         // swizzled source chunk (×8 halfwords)

    const f16* gA[4]; const f16* gBg[4]; const f16* gBu[4];
    f16 *lA[4], *lBg[4], *lBu[4];
#pragma unroll
    for (int it = 0; it < 4; ++it) {
        int slab = it * 4 + w;
        int row = slab * 8 + rsl;
        int lr2 = rt * 128 + row; if (lr2 > count - 1) lr2 = count - 1;
        int t = tok[e * T_TOK + lr2];
        gA[it] = xb + (size_t)t * H_DIM + chk * 8;
        int brow = ct * 128 + row;
        gBg[it] = wgh + ((size_t)e * I_DIM + brow) * H_DIM + chk * 8;
        gBu[it] = wuh + ((size_t)e * I_DIM + brow) * H_DIM + chk * 8;
        lA[it]  = &As[slab * 8 * 64];
        lBg[it] = &Bg[slab * 8 * 64];
        lBu[it] = &Bu[slab * 8 * 64];
    }

    f32x4 accg[4][4], accu[4][4];
#pragma unroll
    for (int i = 0; i < 4; ++i)
#pragma unroll
        for (int j = 0; j < 4; ++j) { accg[i][j] = (f32x4)0.f; accu[i][j] = (f32x4)0.f; }

    for (int ks = 0; ks < H_DIM / 64; ++ks) {
        const int k0 = ks * 64;
#pragma unroll
        for (int it = 0; it < 4; ++it) {
            async_copy16(gA[it] + k0, lA[it]);
            async_copy16(gBg[it] + k0, lBg[it]);
            async_copy16(gBu[it] + k0, lBu[it]);
        }
        __syncthreads();
#pragma unroll
        for (int kk = 0; kk < 64; kk += 32) {
            const int kc = kk >> 3;  // chunk base: 0 or 4
            f16x8 af[4], bg[4], bu[4];
#pragma unroll
            for (int mi = 0; mi < 4; ++mi) {
                int r = wm * 64 + mi * 16 + lc;
                af[mi] = *(const f16x8*)&As[r * 64 + (((qr + kc) ^ (lc & 7)) << 3)];
            }
#pragma unroll
            for (int ni = 0; ni < 4; ++ni) {
                int r = wn * 64 + ni * 16 + lc;
                int o = r * 64 + (((qr + kc) ^ (lc & 7)) << 3);
                bg[ni] = *(const f16x8*)&Bg[o];
                bu[ni] = *(const f16x8*)&Bu[o];
            }
#pragma unroll
            for (int mi = 0; mi < 4; ++mi)
#pragma unroll
                for (int ni = 0; ni < 4; ++ni) {
                    accg[mi][ni] = __builtin_amdgcn_mfma_f32_16x16x32_f16(af[mi], bg[ni], accg[mi][ni], 0, 0, 0);
                    accu[mi][ni] = __builtin_amdgcn_mfma_f32_16x16x32_f16(af[mi], bu[ni], accu[mi][ni], 0, 0, 0);
                }
        }
        __syncthreads();
    }
    // epilogue: silu(g)*u -> mid fp16
#pragma unroll
    for (int mi = 0; mi < 4; ++mi)
#pragma unroll
        for (int ni = 0; ni < 4; ++ni)
#pragma unroll
            for (int r = 0; r < 4; ++r) {
                int lrow = rt * 128 + wm * 64 + mi * 16 + qr * 4 + r;
                if (lrow < count) {
                    float g = accg[mi][ni][r], u = accu[mi][ni][r];
                    float s = g / (1.f + __expf(-g)) * u;
                    mid[(size_t)(offs_e + lrow) * I_DIM + ct * 128 + wn * 64 + ni * 16 + lc] = (f16)s;
                }
            }
}

// ---------------- DOWN: out[t] += w * (mid_e * Wd^T), atomic scatter ----------------
__global__ __launch_bounds__(256) void down_kernel(
    const f16* __restrict__ mid, const f16* __restrict__ wdh,
    const int* __restrict__ cnt, const int* __restrict__ offs,
    const int* __restrict__ tok, const float* __restrict__ wl,
    float* __restrict__ out) {
    const int e = blockIdx.z, rt = blockIdx.y, ct = blockIdx.x;  // ct: 0..7
    const int count = cnt[e];
    if (rt * 128 >= count) return;
    const int offs_e = offs[e];

    __shared__ f16 As[128 * 64];
    __shared__ f16 Bd[128 * 64];

    const int tid = threadIdx.x;
    const int w = tid >> 6, lane = tid & 63;
    const int wm = w & 1, wn = w >> 1;
    const int qr = lane >> 4, lc = lane & 15;

    const int rsl = lane >> 3;
    const int chk = (lane & 7) ^ rsl;

    const f16* gA[4]; const f16* gBd[4];
    f16 *lA[4], *lBd[4];
#pragma unroll
    for (int it = 0; it < 4; ++it) {
        int slab = it * 4 + w;
        int row = slab * 8 + rsl;
        int lr2 = rt * 128 + row; if (lr2 > count - 1) lr2 = count - 1;
        gA[it] = mid + (size_t)(offs_e + lr2) * I_DIM + chk * 8;
        int brow = ct * 128 + row;
        gBd[it] = wdh + ((size_t)e * H_DIM + brow) * I_DIM + chk * 8;
        lA[it]  = &As[slab * 8 * 64];
        lBd[it] = &Bd[slab * 8 * 64];
    }

    f32x4 acc[4][4];
#pragma unroll
    for (int i = 0; i < 4; ++i)
#pragma unroll
        for (int j = 0; j < 4; ++j) acc[i][j] = (f32x4)0.f;

    for (int ks = 0; ks < I_DIM / 64; ++ks) {
        const int k0 = ks * 64;
#pragma unroll
        for (int it = 0; it < 4; ++it) {
            async_copy16(gA[it] + k0, lA[it]);
            async_copy16(gBd[it] + k0, lBd[it]);
        }
        __syncthreads();
#pragma unroll
        for (int kk = 0; kk < 64; kk += 32) {
            const int kc = kk >> 3;
            f16x8 af[4], bf[4];
#pragma unroll
            for (int mi = 0; mi < 4; ++mi) {
                int r = wm * 64 + mi * 16 + lc;
                af[mi] = *(const f16x8*)&As[r * 64 + (((qr + kc) ^ (lc & 7)) << 3)];
            }
#pragma unroll
            for (int ni = 0; ni < 4; ++ni) {
                int r = wn * 64 + ni * 16 + lc;
                bf[ni] = *(const f16x8*)&Bd[r * 64 + (((qr + kc) ^ (lc & 7)) << 3)];
            }
#pragma unroll
            for (int mi = 0; mi < 4; ++mi)
#pragma unroll
                for (int ni = 0; ni < 4; ++ni)
                    acc[mi][ni] = __builtin_amdgcn_mfma_f32_16x16x32_f16(af[mi], bf[ni], acc[mi][ni], 0, 0, 0);
        }
        __syncthreads();
    }
#pragma unroll
    for (int mi = 0; mi < 4; ++mi)
#pragma unroll
        for (int ni = 0; ni < 4; ++ni)
#pragma unroll
            for (int r = 0; r < 4; ++r) {
                int lrow = rt * 128 + wm * 64 + mi * 16 + qr * 4 + r;
                if (lrow < count) {
                    int t = tok[e * T_TOK + lrow];
                    float wt = wl[e * T_TOK + lrow];
                    atomicAdd(&out[(size_t)t * H_DIM + ct * 128 + wn * 64 + ni * 16 + lc],
                              wt * acc[mi][ni][r]);
                }
            }
}

extern "C" void kernel_launch(void* const* d_in, const int* in_sizes, int n_in,
                              void* d_out, int out_size, void* d_ws, size_t ws_size,
                              hipStream_t stream) {
    (void)in_sizes; (void)n_in; (void)out_size; (void)ws_size;
    const float* x  = (const float*)d_in[0];
    const float* rw = (const float*)d_in[1];
    const float* wg = (const float*)d_in[2];
    const float* wu = (const float*)d_in[3];
    const float* wd = (const float*)d_in[4];
    float* out = (float*)d_out;

    uint8_t* ws = (uint8_t*)d_ws;
    int*   cnt  = (int*)(ws + 0);
    int*   offs = (int*)(ws + 64);
    int*   tok  = (int*)(ws + 4096);                       // 8*8192 ints   = 262144 B
    float* wl   = (float*)(ws + 4096 + 262144);            // 8*8192 floats = 262144 B
    f16*   xb   = (f16*)(ws + 528384);                     // 8192*1024 f16  = 16,777,216 B
    f16*   mid  = (f16*)(ws + 17305600);                   // 16384*2048 f16 = 67,108,864 B
    f16*   wgh  = (f16*)(ws + 84414464);                   // 8*2048*1024 f16 = 33,554,432 B
    f16*   wuh  = (f16*)(ws + 117968896);                  // 33,554,432 B
    f16*   wdh  = (f16*)(ws + 151523328);                  // 33,554,432 B
    // total ws use: 185,077,760 B

    hipLaunchKernelGGL(init_kernel, dim3(8192), dim3(256), 0, stream, (fvec4*)out, cnt);
    hipLaunchKernelGGL(cvt_x_kernel, dim3(4096), dim3(256), 0, stream, x, xb);
    hipLaunchKernelGGL(cvt_w_kernel, dim3(8192, 3), dim3(256), 0, stream, wg, wu, wd, wgh, wuh, wdh);
    hipLaunchKernelGGL(router_kernel, dim3(2048), dim3(256), 0, stream, x, rw, cnt, tok, wl);
    hipLaunchKernelGGL(scan_kernel, dim3(1), dim3(64), 0, stream, cnt, offs);
    hipLaunchKernelGGL(gu_kernel, dim3(16, 64, 8), dim3(256), 0, stream, xb, wgh, wuh, cnt, offs, tok, mid);
    hipLaunchKernelGGL(down_kernel, dim3(8, 64, 8), dim3(256), 0, stream, mid, wdh, cnt, offs, tok, wl, out);
}

// Round 4
// 962.184 us; speedup vs baseline: 1.0944x; 1.0403x over previous
//
#include <hip/hip_runtime.h>
#include <stdint.h>

#define H_DIM 1024
#define I_DIM 2048
#define NEXP 8
#define T_TOK 8192

typedef _Float16 f16;
typedef __attribute__((ext_vector_type(2))) __fp16 fp16x2;
typedef __attribute__((ext_vector_type(8))) _Float16 f16x8;
typedef __attribute__((ext_vector_type(4))) float fvec4;
typedef __attribute__((ext_vector_type(4))) float f32x4;
typedef __attribute__((ext_vector_type(4))) unsigned int uvec4;

union H8 { fp16x2 h2[4]; uvec4 v; };

__device__ __forceinline__ void async_copy16(const void* g, void* l) {
    __builtin_amdgcn_global_load_lds(
        (__attribute__((address_space(1))) void*)(uintptr_t)g,
        (__attribute__((address_space(3))) void*)l,
        16, 0, 0);
}

// ---------------- init: zero expert counts ----------------
__global__ void init_kernel(int* __restrict__ cnt) {
    if (threadIdx.x < NEXP) cnt[threadIdx.x] = 0;
}

// ---------------- convert x fp32 -> fp16 ----------------
__global__ void cvt_x_kernel(const float* __restrict__ x, f16* __restrict__ xb) {
    size_t i = (size_t)blockIdx.x * 256 + threadIdx.x;
    const fvec4* p = (const fvec4*)x + i * 2;
    fvec4 a = p[0], b = p[1];
    H8 h;
    h.h2[0] = __builtin_amdgcn_cvt_pkrtz(a.x, a.y);
    h.h2[1] = __builtin_amdgcn_cvt_pkrtz(a.z, a.w);
    h.h2[2] = __builtin_amdgcn_cvt_pkrtz(b.x, b.y);
    h.h2[3] = __builtin_amdgcn_cvt_pkrtz(b.z, b.w);
    ((uvec4*)xb)[i] = h.v;
}

// ---------------- convert weights fp32 -> fp16 ----------------
__global__ void cvt_w_kernel(const float* __restrict__ wg, const float* __restrict__ wu,
                             const float* __restrict__ wd,
                             f16* __restrict__ wgh, f16* __restrict__ wuh,
                             f16* __restrict__ wdh) {
    const float* src; f16* dst;
    if (blockIdx.y == 0)      { src = wg; dst = wgh; }
    else if (blockIdx.y == 1) { src = wu; dst = wuh; }
    else                      { src = wd; dst = wdh; }
    size_t i = (size_t)blockIdx.x * 256 + threadIdx.x;
    const fvec4* p = (const fvec4*)src + i * 2;
    fvec4 a = p[0], b = p[1];
    H8 h;
    h.h2[0] = __builtin_amdgcn_cvt_pkrtz(a.x, a.y);
    h.h2[1] = __builtin_amdgcn_cvt_pkrtz(a.z, a.w);
    h.h2[2] = __builtin_amdgcn_cvt_pkrtz(b.x, b.y);
    h.h2[3] = __builtin_amdgcn_cvt_pkrtz(b.z, b.w);
    ((uvec4*)dst)[i] = h.v;
}

// ---------------- router: fp32 logits, top-2, expert lists + token slot map ----------------
__global__ void router_kernel(const float* __restrict__ x, const float* __restrict__ rw,
                              int* __restrict__ cnt, int* __restrict__ tok,
                              int* __restrict__ sl, float* __restrict__ sw) {
    int wid = (blockIdx.x * blockDim.x + threadIdx.x) >> 6;
    int lane = threadIdx.x & 63;
    if (wid >= T_TOK) return;
    const fvec4* xr = (const fvec4*)(x + (size_t)wid * H_DIM);
    float acc[NEXP];
#pragma unroll
    for (int e = 0; e < NEXP; ++e) acc[e] = 0.f;
#pragma unroll
    for (int p = 0; p < 4; ++p) {
        int c4 = p * 64 + lane;
        fvec4 xv = xr[c4];
#pragma unroll
        for (int e = 0; e < NEXP; ++e) {
            fvec4 wv = ((const fvec4*)(rw + (size_t)e * H_DIM))[c4];
            acc[e] += xv.x * wv.x + xv.y * wv.y + xv.z * wv.z + xv.w * wv.w;
        }
    }
#pragma unroll
    for (int e = 0; e < NEXP; ++e) {
        float v = acc[e];
#pragma unroll
        for (int s = 32; s > 0; s >>= 1) v += __shfl_xor(v, s, 64);
        acc[e] = v;
    }
    if (lane == 0) {
        int i0 = 0; float m0 = acc[0];
#pragma unroll
        for (int e = 1; e < NEXP; ++e) if (acc[e] > m0) { m0 = acc[e]; i0 = e; }
        int i1 = -1; float m1 = -1e30f;
#pragma unroll
        for (int e = 0; e < NEXP; ++e) if (e != i0 && acc[e] > m1) { m1 = acc[e]; i1 = e; }
        float w0 = 1.f / (1.f + __expf(m1 - m0));
        float w1 = 1.f - w0;
        int p0 = atomicAdd(&cnt[i0], 1);
        tok[i0 * T_TOK + p0] = wid;
        sl[wid * 2] = (i0 << 20) | p0;  sw[wid * 2] = w0;
        int p1 = atomicAdd(&cnt[i1], 1);
        tok[i1 * T_TOK + p1] = wid;
        sl[wid * 2 + 1] = (i1 << 20) | p1;  sw[wid * 2 + 1] = w1;
    }
}

__global__ void scan_kernel(const int* __restrict__ cnt, int* __restrict__ offs) {
    if (threadIdx.x == 0) {
        int s = 0;
        for (int e = 0; e < NEXP; ++e) { offs[e] = s; s += cnt[e]; }
    }
}

// LDS row = 64 halfwords = 8 chunks of 16B; chunk c of row r lives at chunk c^(r&7).
// Staging lane l writes LDS chunk (l&7) of slab-row (l>>3) -> fetch global chunk (l&7)^(l>>3).

// ---------------- GU: M=256 x N=64 tile, grid (e, ct, rt) x-major for XCD locality ----------
__global__ __launch_bounds__(256) void gu_kernel(
    const f16* __restrict__ xb, const f16* __restrict__ wgh, const f16* __restrict__ wuh,
    const int* __restrict__ cnt, const int* __restrict__ offs,
    const int* __restrict__ tok, f16* __restrict__ mid) {
    const int e = blockIdx.x, ct = blockIdx.y, rt = blockIdx.z;
    const int count = cnt[e];
    if (rt * 256 >= count) return;
    const int offs_e = offs[e];

    __shared__ f16 As[256 * 64];   // 32 KB
    __shared__ f16 Bg[64 * 64];    // 8 KB
    __shared__ f16 Bu[64 * 64];    // 8 KB

    const int tid = threadIdx.x;
    const int w = tid >> 6, lane = tid & 63;
    const int qr = lane >> 4, lc = lane & 15;
    const int rsl = lane >> 3;
    const int chk = (lane & 7) ^ rsl;

    const f16* gA[8]; f16* lA[8];
#pragma unroll
    for (int it = 0; it < 8; ++it) {
        int slab = it * 4 + w;               // 0..31
        int row = slab * 8 + rsl;            // 0..255
        int lr2 = rt * 256 + row; if (lr2 > count - 1) lr2 = count - 1;
        int t = tok[e * T_TOK + lr2];
        gA[it] = xb + (size_t)t * H_DIM + chk * 8;
        lA[it] = &As[slab * 512];
    }
    const f16* gBg[2]; const f16* gBu[2]; f16 *lBg[2], *lBu[2];
#pragma unroll
    for (int it = 0; it < 2; ++it) {
        int slab = it * 4 + w;               // 0..7
        int row = slab * 8 + rsl;            // 0..63
        int brow = ct * 64 + row;
        gBg[it] = wgh + ((size_t)e * I_DIM + brow) * H_DIM + chk * 8;
        gBu[it] = wuh + ((size_t)e * I_DIM + brow) * H_DIM + chk * 8;
        lBg[it] = &Bg[slab * 512];
        lBu[it] = &Bu[slab * 512];
    }

    f32x4 accg[4][4], accu[4][4];
#pragma unroll
    for (int i = 0; i < 4; ++i)
#pragma unroll
        for (int j = 0; j < 4; ++j) { accg[i][j] = (f32x4)0.f; accu[i][j] = (f32x4)0.f; }

    for (int ks = 0; ks < H_DIM / 64; ++ks) {
        const int k0 = ks * 64;
#pragma unroll
        for (int it = 0; it < 8; ++it) async_copy16(gA[it] + k0, lA[it]);
#pragma unroll
        for (int it = 0; it < 2; ++it) {
            async_copy16(gBg[it] + k0, lBg[it]);
            async_copy16(gBu[it] + k0, lBu[it]);
        }
        __syncthreads();
#pragma unroll
        for (int kk = 0; kk < 2; ++kk) {
            const int kc = kk * 4;
            const int coff = (((qr + kc) ^ (lc & 7)) << 3);
            f16x8 af[4], bg[4], bu[4];
#pragma unroll
            for (int mi = 0; mi < 4; ++mi) {
                int r = w * 64 + mi * 16 + lc;       // 0..255
                af[mi] = *(const f16x8*)&As[r * 64 + coff];
            }
#pragma unroll
            for (int ni = 0; ni < 4; ++ni) {
                int r = ni * 16 + lc;                // 0..63
                bg[ni] = *(const f16x8*)&Bg[r * 64 + coff];
                bu[ni] = *(const f16x8*)&Bu[r * 64 + coff];
            }
#pragma unroll
            for (int mi = 0; mi < 4; ++mi)
#pragma unroll
                for (int ni = 0; ni < 4; ++ni) {
                    accg[mi][ni] = __builtin_amdgcn_mfma_f32_16x16x32_f16(af[mi], bg[ni], accg[mi][ni], 0, 0, 0);
                    accu[mi][ni] = __builtin_amdgcn_mfma_f32_16x16x32_f16(af[mi], bu[ni], accu[mi][ni], 0, 0, 0);
                }
        }
        __syncthreads();
    }
#pragma unroll
    for (int mi = 0; mi < 4; ++mi)
#pragma unroll
        for (int ni = 0; ni < 4; ++ni)
#pragma unroll
            for (int r = 0; r < 4; ++r) {
                int lrow = rt * 256 + w * 64 + mi * 16 + qr * 4 + r;
                if (lrow < count) {
                    float g = accg[mi][ni][r], u = accu[mi][ni][r];
                    float s = g / (1.f + __expf(-g)) * u;
                    mid[(size_t)(offs_e + lrow) * I_DIM + ct * 64 + ni * 16 + lc] = (f16)s;
                }
            }
}

// ---------------- DOWN: M=128 x N=256 tile, plain fp32 stores into slot buffer ----------
__global__ __launch_bounds__(256) void down_kernel(
    const f16* __restrict__ mid, const f16* __restrict__ wdh,
    const int* __restrict__ cnt, const int* __restrict__ offs,
    float* __restrict__ mid2) {
    const int e = blockIdx.x, ct = blockIdx.y, rt = blockIdx.z;  // ct: 0..3
    const int count = cnt[e];
    if (rt * 128 >= count) return;
    const int offs_e = offs[e];

    __shared__ f16 As[128 * 64];   // 16 KB
    __shared__ f16 Bd[256 * 64];   // 32 KB

    const int tid = threadIdx.x;
    const int w = tid >> 6, lane = tid & 63;
    const int wm = w & 1, wn = w >> 1;
    const int qr = lane >> 4, lc = lane & 15;
    const int rsl = lane >> 3;
    const int chk = (lane & 7) ^ rsl;

    const f16* gA[4]; f16* lA[4];
#pragma unroll
    for (int it = 0; it < 4; ++it) {
        int slab = it * 4 + w;               // 0..15
        int row = slab * 8 + rsl;
        int lr2 = rt * 128 + row; if (lr2 > count - 1) lr2 = count - 1;
        gA[it] = mid + (size_t)(offs_e + lr2) * I_DIM + chk * 8;
        lA[it] = &As[slab * 512];
    }
    const f16* gBd[8]; f16* lBd[8];
#pragma unroll
    for (int it = 0; it < 8; ++it) {
        int slab = it * 4 + w;               // 0..31
        int row = slab * 8 + rsl;            // 0..255
        int brow = ct * 256 + row;
        gBd[it] = wdh + ((size_t)e * H_DIM + brow) * I_DIM + chk * 8;
        lBd[it] = &Bd[slab * 512];
    }

    f32x4 acc[4][8];
#pragma unroll
    for (int i = 0; i < 4; ++i)
#pragma unroll
        for (int j = 0; j < 8; ++j) acc[i][j] = (f32x4)0.f;

    for (int ks = 0; ks < I_DIM / 64; ++ks) {
        const int k0 = ks * 64;
#pragma unroll
        for (int it = 0; it < 4; ++it) async_copy16(gA[it] + k0, lA[it]);
#pragma unroll
        for (int it = 0; it < 8; ++it) async_copy16(gBd[it] + k0, lBd[it]);
        __syncthreads();
#pragma unroll
        for (int kk = 0; kk < 2; ++kk) {
            const int kc = kk * 4;
            const int coff = (((qr + kc) ^ (lc & 7)) << 3);
            f16x8 af[4], bf[8];
#pragma unroll
            for (int mi = 0; mi < 4; ++mi) {
                int r = wm * 64 + mi * 16 + lc;      // 0..127
                af[mi] = *(const f16x8*)&As[r * 64 + coff];
            }
#pragma unroll
            for (int ni = 0; ni < 8; ++ni) {
                int r = wn * 128 + ni * 16 + lc;     // 0..255
                bf[ni] = *(const f16x8*)&Bd[r * 64 + coff];
            }
#pragma unroll
            for (int mi = 0; mi < 4; ++mi)
#pragma unroll
                for (int ni = 0; ni < 8; ++ni)
                    acc[mi][ni] = __builtin_amdgcn_mfma_f32_16x16x32_f16(af[mi], bf[ni], acc[mi][ni], 0, 0, 0);
        }
        __syncthreads();
    }
#pragma unroll
    for (int mi = 0; mi < 4; ++mi)
#pragma unroll
        for (int ni = 0; ni < 8; ++ni)
#pragma unroll
            for (int r = 0; r < 4; ++r) {
                int lrow = rt * 128 + wm * 64 + mi * 16 + qr * 4 + r;
                if (lrow < count) {
                    int col = ct * 256 + wn * 128 + ni * 16 + lc;
                    mid2[(size_t)(offs_e + lrow) * H_DIM + col] = acc[mi][ni][r];
                }
            }
}

// ---------------- combine: out[t] = w0*mid2[slot0] + w1*mid2[slot1] ----------------
__global__ void combine_kernel(const float* __restrict__ mid2, const int* __restrict__ sl,
                               const float* __restrict__ sw, const int* __restrict__ offs,
                               fvec4* __restrict__ out) {
    const int t = blockIdx.x;
    const int c = threadIdx.x;               // 0..255 float4 per 1024-col row
    int s0 = sl[t * 2], s1 = sl[t * 2 + 1];
    float w0 = sw[t * 2], w1 = sw[t * 2 + 1];
    size_t r0 = (size_t)(offs[s0 >> 20] + (s0 & 0xFFFFF)) * 256 + c;
    size_t r1 = (size_t)(offs[s1 >> 20] + (s1 & 0xFFFFF)) * 256 + c;
    const fvec4* m4 = (const fvec4*)mid2;
    fvec4 a = m4[r0], b = m4[r1];
    out[(size_t)t * 256 + c] = w0 * a + w1 * b;
}

extern "C" void kernel_launch(void* const* d_in, const int* in_sizes, int n_in,
                              void* d_out, int out_size, void* d_ws, size_t ws_size,
                              hipStream_t stream) {
    (void)in_sizes; (void)n_in; (void)out_size; (void)ws_size;
    const float* x  = (const float*)d_in[0];
    const float* rw = (const float*)d_in[1];
    const float* wg = (const float*)d_in[2];
    const float* wu = (const float*)d_in[3];
    const float* wd = (const float*)d_in[4];
    float* out = (float*)d_out;

    uint8_t* ws = (uint8_t*)d_ws;
    int*   cnt  = (int*)(ws + 0);
    int*   offs = (int*)(ws + 64);
    int*   tok  = (int*)(ws + 4096);           // 8*8192 ints = 262144 B
    int*   sl   = (int*)(ws + 266240);         // 2*8192 ints = 65536 B
    float* sw   = (float*)(ws + 331776);       // 2*8192 floats = 65536 B
    f16*   xb   = (f16*)(ws + 528384);         // 16,777,216 B
    f16*   mid  = (f16*)(ws + 17305600);       // 16384*2048 f16 = 67,108,864 B
    f16*   wgh  = (f16*)(ws + 84414464);       // 33,554,432 B
    f16*   wuh  = (f16*)(ws + 117968896);      // 33,554,432 B
    f16*   wdh  = (f16*)(ws + 151523328);      // 33,554,432 B  (end 185,077,760)
    // mid2 fp32 [16384][1024] overlays wgh+wuh (dead after gu; rewritten by cvt_w each call)
    float* mid2 = (float*)(ws + 84414464);     // 67,108,864 B

    hipLaunchKernelGGL(init_kernel, dim3(1), dim3(64), 0, stream, cnt);
    hipLaunchKernelGGL(cvt_x_kernel, dim3(4096), dim3(256), 0, stream, x, xb);
    hipLaunchKernelGGL(cvt_w_kernel, dim3(8192, 3), dim3(256), 0, stream, wg, wu, wd, wgh, wuh, wdh);
    hipLaunchKernelGGL(router_kernel, dim3(2048), dim3(256), 0, stream, x, rw, cnt, tok, sl, sw);
    hipLaunchKernelGGL(scan_kernel, dim3(1), dim3(64), 0, stream, cnt, offs);
    // grid.x = expert (8) -> round-robin XCD assignment pins each expert to one XCD's L2
    hipLaunchKernelGGL(gu_kernel, dim3(8, 32, 32), dim3(256), 0, stream, xb, wgh, wuh, cnt, offs, tok, mid);
    hipLaunchKernelGGL(down_kernel, dim3(8, 4, 64), dim3(256), 0, stream, mid, wdh, cnt, offs, mid2);
    hipLaunchKernelGGL(combine_kernel, dim3(8192), dim3(256), 0, stream, mid2, sl, sw, offs, (fvec4*)out);
}

// Round 5
// 737.025 us; speedup vs baseline: 1.4287x; 1.3055x over previous
//
#include <hip/hip_runtime.h>
#include <stdint.h>

#define H_DIM 1024
#define I_DIM 2048
#define NEXP 8
#define T_TOK 8192

typedef _Float16 f16;
typedef __attribute__((ext_vector_type(2))) __fp16 fp16x2;
typedef __attribute__((ext_vector_type(8))) _Float16 f16x8;
typedef __attribute__((ext_vector_type(4))) float fvec4;
typedef __attribute__((ext_vector_type(4))) float f32x4;
typedef __attribute__((ext_vector_type(4))) unsigned int uvec4;

union H8 { fp16x2 h2[4]; uvec4 v; };

__device__ __forceinline__ void async_copy16(const void* g, void* l) {
    __builtin_amdgcn_global_load_lds(
        (__attribute__((address_space(1))) void*)(uintptr_t)g,
        (__attribute__((address_space(3))) void*)l,
        16, 0, 0);
}

// ---------------- init: zero expert counts ----------------
__global__ void init_kernel(int* __restrict__ cnt) {
    if (threadIdx.x < NEXP) cnt[threadIdx.x] = 0;
}

// ---------------- convert x fp32 -> fp16 ----------------
__global__ void cvt_x_kernel(const float* __restrict__ x, f16* __restrict__ xb) {
    size_t i = (size_t)blockIdx.x * 256 + threadIdx.x;
    const fvec4* p = (const fvec4*)x + i * 2;
    fvec4 a = p[0], b = p[1];
    H8 h;
    h.h2[0] = __builtin_amdgcn_cvt_pkrtz(a.x, a.y);
    h.h2[1] = __builtin_amdgcn_cvt_pkrtz(a.z, a.w);
    h.h2[2] = __builtin_amdgcn_cvt_pkrtz(b.x, b.y);
    h.h2[3] = __builtin_amdgcn_cvt_pkrtz(b.z, b.w);
    ((uvec4*)xb)[i] = h.v;
}

// ---------------- convert weights fp32 -> fp16 ----------------
__global__ void cvt_w_kernel(const float* __restrict__ wg, const float* __restrict__ wu,
                             const float* __restrict__ wd,
                             f16* __restrict__ wgh, f16* __restrict__ wuh,
                             f16* __restrict__ wdh) {
    const float* src; f16* dst;
    if (blockIdx.y == 0)      { src = wg; dst = wgh; }
    else if (blockIdx.y == 1) { src = wu; dst = wuh; }
    else                      { src = wd; dst = wdh; }
    size_t i = (size_t)blockIdx.x * 256 + threadIdx.x;
    const fvec4* p = (const fvec4*)src + i * 2;
    fvec4 a = p[0], b = p[1];
    H8 h;
    h.h2[0] = __builtin_amdgcn_cvt_pkrtz(a.x, a.y);
    h.h2[1] = __builtin_amdgcn_cvt_pkrtz(a.z, a.w);
    h.h2[2] = __builtin_amdgcn_cvt_pkrtz(b.x, b.y);
    h.h2[3] = __builtin_amdgcn_cvt_pkrtz(b.z, b.w);
    ((uvec4*)dst)[i] = h.v;
}

// ---------------- router ----------------
__global__ void router_kernel(const float* __restrict__ x, const float* __restrict__ rw,
                              int* __restrict__ cnt, int* __restrict__ tok,
                              int* __restrict__ sl, float* __restrict__ sw) {
    int wid = (blockIdx.x * blockDim.x + threadIdx.x) >> 6;
    int lane = threadIdx.x & 63;
    if (wid >= T_TOK) return;
    const fvec4* xr = (const fvec4*)(x + (size_t)wid * H_DIM);
    float acc[NEXP];
#pragma unroll
    for (int e = 0; e < NEXP; ++e) acc[e] = 0.f;
#pragma unroll
    for (int p = 0; p < 4; ++p) {
        int c4 = p * 64 + lane;
        fvec4 xv = xr[c4];
#pragma unroll
        for (int e = 0; e < NEXP; ++e) {
            fvec4 wv = ((const fvec4*)(rw + (size_t)e * H_DIM))[c4];
            acc[e] += xv.x * wv.x + xv.y * wv.y + xv.z * wv.z + xv.w * wv.w;
        }
    }
#pragma unroll
    for (int e = 0; e < NEXP; ++e) {
        float v = acc[e];
#pragma unroll
        for (int s = 32; s > 0; s >>= 1) v += __shfl_xor(v, s, 64);
        acc[e] = v;
    }
    if (lane == 0) {
        int i0 = 0; float m0 = acc[0];
#pragma unroll
        for (int e = 1; e < NEXP; ++e) if (acc[e] > m0) { m0 = acc[e]; i0 = e; }
        int i1 = -1; float m1 = -1e30f;
#pragma unroll
        for (int e = 0; e < NEXP; ++e) if (e != i0 && acc[e] > m1) { m1 = acc[e]; i1 = e; }
        float w0 = 1.f / (1.f + __expf(m1 - m0));
        float w1 = 1.f - w0;
        int p0 = atomicAdd(&cnt[i0], 1);
        tok[i0 * T_TOK + p0] = wid;
        sl[wid * 2] = (i0 << 20) | p0;  sw[wid * 2] = w0;
        int p1 = atomicAdd(&cnt[i1], 1);
        tok[i1 * T_TOK + p1] = wid;
        sl[wid * 2 + 1] = (i1 << 20) | p1;  sw[wid * 2 + 1] = w1;
    }
}

__global__ void scan_kernel(const int* __restrict__ cnt, int* __restrict__ offs) {
    if (threadIdx.x == 0) {
        int s = 0;
        for (int e = 0; e < NEXP; ++e) { offs[e] = s; s += cnt[e]; }
    }
}

// LDS row = 64 halfwords = 8 chunks of 16B; chunk c of row r lives at chunk c^(r&7).
// Staging lane l writes LDS chunk (l&7) of slab-row (l>>3) -> fetch global chunk (l&7)^(l>>3).

// ---------------- GU: M=128 x N=64 tile, 32 KB LDS, 64-reg acc/wave ----------------
__global__ __launch_bounds__(256) void gu_kernel(
    const f16* __restrict__ xb, const f16* __restrict__ wgh, const f16* __restrict__ wuh,
    const int* __restrict__ cnt, const int* __restrict__ offs,
    const int* __restrict__ tok, f16* __restrict__ mid) {
    const int e = blockIdx.x, ct = blockIdx.y, rt = blockIdx.z;
    const int count = cnt[e];
    if (rt * 128 >= count) return;
    const int offs_e = offs[e];

    __shared__ f16 As[128 * 64];   // 16 KB
    __shared__ f16 Bg[64 * 64];    // 8 KB
    __shared__ f16 Bu[64 * 64];    // 8 KB

    const int tid = threadIdx.x;
    const int w = tid >> 6, lane = tid & 63;
    const int qr = lane >> 4, lc = lane & 15;
    const int rsl = lane >> 3;
    const int chk = (lane & 7) ^ rsl;

    const f16* gA[4]; f16* lA[4];
#pragma unroll
    for (int it = 0; it < 4; ++it) {
        int slab = it * 4 + w;               // 0..15
        int row = slab * 8 + rsl;            // 0..127
        int lr2 = rt * 128 + row; if (lr2 > count - 1) lr2 = count - 1;
        int t = tok[e * T_TOK + lr2];
        gA[it] = xb + (size_t)t * H_DIM + chk * 8;
        lA[it] = &As[slab * 512];
    }
    const f16* gBg[2]; const f16* gBu[2]; f16 *lBg[2], *lBu[2];
#pragma unroll
    for (int it = 0; it < 2; ++it) {
        int slab = it * 4 + w;               // 0..7
        int row = slab * 8 + rsl;            // 0..63
        int brow = ct * 64 + row;
        gBg[it] = wgh + ((size_t)e * I_DIM + brow) * H_DIM + chk * 8;
        gBu[it] = wuh + ((size_t)e * I_DIM + brow) * H_DIM + chk * 8;
        lBg[it] = &Bg[slab * 512];
        lBu[it] = &Bu[slab * 512];
    }

    // per-wave: M-strip w*32..w*32+31 (mi 0..1), all 64 N cols (ni 0..3), 2 matrices
    f32x4 accg[2][4], accu[2][4];
#pragma unroll
    for (int i = 0; i < 2; ++i)
#pragma unroll
        for (int j = 0; j < 4; ++j) { accg[i][j] = (f32x4)0.f; accu[i][j] = (f32x4)0.f; }

    for (int ks = 0; ks < H_DIM / 64; ++ks) {
        const int k0 = ks * 64;
#pragma unroll
        for (int it = 0; it < 4; ++it) async_copy16(gA[it] + k0, lA[it]);
#pragma unroll
        for (int it = 0; it < 2; ++it) {
            async_copy16(gBg[it] + k0, lBg[it]);
            async_copy16(gBu[it] + k0, lBu[it]);
        }
        __syncthreads();
#pragma unroll
        for (int kk = 0; kk < 2; ++kk) {
            const int kc = kk * 4;
            const int coff = (((qr + kc) ^ (lc & 7)) << 3);
            f16x8 af[2], bg[4], bu[4];
#pragma unroll
            for (int mi = 0; mi < 2; ++mi) {
                int r = w * 32 + mi * 16 + lc;       // 0..127
                af[mi] = *(const f16x8*)&As[r * 64 + coff];
            }
#pragma unroll
            for (int ni = 0; ni < 4; ++ni) {
                int r = ni * 16 + lc;                // 0..63
                bg[ni] = *(const f16x8*)&Bg[r * 64 + coff];
                bu[ni] = *(const f16x8*)&Bu[r * 64 + coff];
            }
#pragma unroll
            for (int mi = 0; mi < 2; ++mi)
#pragma unroll
                for (int ni = 0; ni < 4; ++ni) {
                    accg[mi][ni] = __builtin_amdgcn_mfma_f32_16x16x32_f16(af[mi], bg[ni], accg[mi][ni], 0, 0, 0);
                    accu[mi][ni] = __builtin_amdgcn_mfma_f32_16x16x32_f16(af[mi], bu[ni], accu[mi][ni], 0, 0, 0);
                }
        }
        __syncthreads();
    }
#pragma unroll
    for (int mi = 0; mi < 2; ++mi)
#pragma unroll
        for (int ni = 0; ni < 4; ++ni)
#pragma unroll
            for (int r = 0; r < 4; ++r) {
                int lrow = rt * 128 + w * 32 + mi * 16 + qr * 4 + r;
                if (lrow < count) {
                    float g = accg[mi][ni][r], u = accu[mi][ni][r];
                    float s = g / (1.f + __expf(-g)) * u;
                    mid[(size_t)(offs_e + lrow) * I_DIM + ct * 64 + ni * 16 + lc] = (f16)s;
                }
            }
}

// ---------------- DOWN: M=128 x N=128 (m97 shape), fp32 stores to slot buffer ----------
__global__ __launch_bounds__(256) void down_kernel(
    const f16* __restrict__ mid, const f16* __restrict__ wdh,
    const int* __restrict__ cnt, const int* __restrict__ offs,
    float* __restrict__ mid2) {
    const int e = blockIdx.x, ct = blockIdx.y, rt = blockIdx.z;  // ct: 0..7
    const int count = cnt[e];
    if (rt * 128 >= count) return;
    const int offs_e = offs[e];

    __shared__ f16 As[128 * 64];   // 16 KB
    __shared__ f16 Bd[128 * 64];   // 16 KB

    const int tid = threadIdx.x;
    const int w = tid >> 6, lane = tid & 63;
    const int wm = w & 1, wn = w >> 1;
    const int qr = lane >> 4, lc = lane & 15;
    const int rsl = lane >> 3;
    const int chk = (lane & 7) ^ rsl;

    const f16* gA[4]; f16* lA[4];
#pragma unroll
    for (int it = 0; it < 4; ++it) {
        int slab = it * 4 + w;               // 0..15
        int row = slab * 8 + rsl;
        int lr2 = rt * 128 + row; if (lr2 > count - 1) lr2 = count - 1;
        gA[it] = mid + (size_t)(offs_e + lr2) * I_DIM + chk * 8;
        lA[it] = &As[slab * 512];
    }
    const f16* gBd[4]; f16* lBd[4];
#pragma unroll
    for (int it = 0; it < 4; ++it) {
        int slab = it * 4 + w;               // 0..15
        int row = slab * 8 + rsl;            // 0..127
        int brow = ct * 128 + row;
        gBd[it] = wdh + ((size_t)e * H_DIM + brow) * I_DIM + chk * 8;
        lBd[it] = &Bd[slab * 512];
    }

    f32x4 acc[4][4];
#pragma unroll
    for (int i = 0; i < 4; ++i)
#pragma unroll
        for (int j = 0; j < 4; ++j) acc[i][j] = (f32x4)0.f;

    for (int ks = 0; ks < I_DIM / 64; ++ks) {
        const int k0 = ks * 64;
#pragma unroll
        for (int it = 0; it < 4; ++it) async_copy16(gA[it] + k0, lA[it]);
#pragma unroll
        for (int it = 0; it < 4; ++it) async_copy16(gBd[it] + k0, lBd[it]);
        __syncthreads();
#pragma unroll
        for (int kk = 0; kk < 2; ++kk) {
            const int kc = kk * 4;
            const int coff = (((qr + kc) ^ (lc & 7)) << 3);
            f16x8 af[4], bf[4];
#pragma unroll
            for (int mi = 0; mi < 4; ++mi) {
                int r = wm * 64 + mi * 16 + lc;      // 0..127
                af[mi] = *(const f16x8*)&As[r * 64 + coff];
            }
#pragma unroll
            for (int ni = 0; ni < 4; ++ni) {
                int r = wn * 64 + ni * 16 + lc;      // 0..127
                bf[ni] = *(const f16x8*)&Bd[r * 64 + coff];
            }
#pragma unroll
            for (int mi = 0; mi < 4; ++mi)
#pragma unroll
                for (int ni = 0; ni < 4; ++ni)
                    acc[mi][ni] = __builtin_amdgcn_mfma_f32_16x16x32_f16(af[mi], bf[ni], acc[mi][ni], 0, 0, 0);
        }
        __syncthreads();
    }
#pragma unroll
    for (int mi = 0; mi < 4; ++mi)
#pragma unroll
        for (int ni = 0; ni < 4; ++ni)
#pragma unroll
            for (int r = 0; r < 4; ++r) {
                int lrow = rt * 128 + wm * 64 + mi * 16 + qr * 4 + r;
                if (lrow < count) {
                    int col = ct * 128 + wn * 64 + ni * 16 + lc;
                    mid2[(size_t)(offs_e + lrow) * H_DIM + col] = acc[mi][ni][r];
                }
            }
}

// ---------------- combine: out[t] = w0*mid2[slot0] + w1*mid2[slot1] ----------------
__global__ void combine_kernel(const float* __restrict__ mid2, const int* __restrict__ sl,
                               const float* __restrict__ sw, const int* __restrict__ offs,
                               fvec4* __restrict__ out) {
    const int t = blockIdx.x;
    const int c = threadIdx.x;               // 0..255 float4 per 1024-col row
    int s0 = sl[t * 2], s1 = sl[t * 2 + 1];
    float w0 = sw[t * 2], w1 = sw[t * 2 + 1];
    size_t r0 = (size_t)(offs[s0 >> 20] + (s0 & 0xFFFFF)) * 256 + c;
    size_t r1 = (size_t)(offs[s1 >> 20] + (s1 & 0xFFFFF)) * 256 + c;
    const fvec4* m4 = (const fvec4*)mid2;
    fvec4 a = m4[r0], b = m4[r1];
    out[(size_t)t * 256 + c] = w0 * a + w1 * b;
}

extern "C" void kernel_launch(void* const* d_in, const int* in_sizes, int n_in,
                              void* d_out, int out_size, void* d_ws, size_t ws_size,
                              hipStream_t stream) {
    (void)in_sizes; (void)n_in; (void)out_size; (void)ws_size;
    const float* x  = (const float*)d_in[0];
    const float* rw = (const float*)d_in[1];
    const float* wg = (const float*)d_in[2];
    const float* wu = (const float*)d_in[3];
    const float* wd = (const float*)d_in[4];
    float* out = (float*)d_out;

    uint8_t* ws = (uint8_t*)d_ws;
    int*   cnt  = (int*)(ws + 0);
    int*   offs = (int*)(ws + 64);
    int*   tok  = (int*)(ws + 4096);           // 8*8192 ints = 262144 B
    int*   sl   = (int*)(ws + 266240);         // 2*8192 ints = 65536 B
    float* sw   = (float*)(ws + 331776);       // 2*8192 floats = 65536 B
    f16*   xb   = (f16*)(ws + 528384);         // 16,777,216 B
    f16*   mid  = (f16*)(ws + 17305600);       // 16384*2048 f16 = 67,108,864 B
    f16*   wgh  = (f16*)(ws + 84414464);       // 33,554,432 B
    f16*   wuh  = (f16*)(ws + 117968896);      // 33,554,432 B
    f16*   wdh  = (f16*)(ws + 151523328);      // 33,554,432 B  (end 185,077,760)
    // mid2 fp32 [16384][1024] overlays wgh+wuh (dead after gu; rewritten by cvt_w each call)
    float* mid2 = (float*)(ws + 84414464);     // 67,108,864 B

    hipLaunchKernelGGL(init_kernel, dim3(1), dim3(64), 0, stream, cnt);
    hipLaunchKernelGGL(cvt_x_kernel, dim3(4096), dim3(256), 0, stream, x, xb);
    hipLaunchKernelGGL(cvt_w_kernel, dim3(8192, 3), dim3(256), 0, stream, wg, wu, wd, wgh, wuh, wdh);
    hipLaunchKernelGGL(router_kernel, dim3(2048), dim3(256), 0, stream, x, rw, cnt, tok, sl, sw);
    hipLaunchKernelGGL(scan_kernel, dim3(1), dim3(64), 0, stream, cnt, offs);
    // grid.x = expert (8) -> round-robin XCD assignment pins each expert to one XCD's L2
    hipLaunchKernelGGL(gu_kernel, dim3(8, 32, 64), dim3(256), 0, stream, xb, wgh, wuh, cnt, offs, tok, mid);
    hipLaunchKernelGGL(down_kernel, dim3(8, 8, 64), dim3(256), 0, stream, mid, wdh, cnt, offs, mid2);
    hipLaunchKernelGGL(combine_kernel, dim3(8192), dim3(256), 0, stream, mid2, sl, sw, offs, (fvec4*)out);
}